// Round 1
// baseline (138.063 us; speedup 1.0000x reference)
//
#include <hip/hip_runtime.h>
#include <hip/hip_bf16.h>
#include <math.h>

#define BS    32
#define T     512
#define BT    (BS * T)     // 16384 tokens
#define D     96
#define H     4
#define MX    32           // DST_MXLEN
#define A2MAX 160          // padl for a2len=150

#define QKV_TOK  32        // tokens per qkv block (2 halves x 16)
#define FUSE_TOK 16        // tokens per fuse block

// ---------------------------------------------------------------------------
// Kernel 0 (prep): weight transposes + COO scatter + a2a position flags.
// WT  [97][192]: WT[i*192 + p*64 + c] = wqv[(p*96+32+c)*97 + i]  (i=96 -> bias)
// FWT [65][96] : FWT[i*96 + o]        = fw[o*97 + 32 + i]        (i=64 -> bias)
// srcs[(ci*T+dst)*MX + cnt] = src.
//   NOTE: no memset needed — the problem's COO covers EVERY (dst,cnt) slot
//   exactly once (dst=repeat(arange(T),MX), cnt=tile(arange(MX))).
// flag[t]: computed race-free by binary search of sorted a2a (no scatter,
//   no -1 prefill dispatch).
// ---------------------------------------------------------------------------
__global__ void prep_kernel(const float* __restrict__ wqv, const float* __restrict__ fw,
                            const int* __restrict__ coo0, const int* __restrict__ coo1,
                            const int* __restrict__ a2a, int nedges, int a2len,
                            float* __restrict__ WT, float* __restrict__ FWT,
                            int* __restrict__ srcs, int* __restrict__ flag) {
    int idx = blockIdx.x * blockDim.x + threadIdx.x;
    if (idx < 97 * 192) {
        const int i = idx / 192, oc = idx - 192 * i;
        const int p = oc >> 6, c = oc & 63;
        WT[idx] = wqv[(p * 96 + 32 + c) * 97 + i];
        return;
    }
    idx -= 97 * 192;
    if (idx < 65 * 96) {
        const int i = idx / 96, o = idx - 96 * i;
        FWT[idx] = fw[o * 97 + 32 + i];
        return;
    }
    idx -= 65 * 96;
    if (idx < 2 * nedges) {
        const int ci = idx / nedges;
        const int e  = idx - ci * nedges;
        const int* row = (ci == 0 ? coo0 : coo1) + e * 3;
        const int dst = row[0], src = row[1], cnt = row[2];
        if (dst >= 0 && dst < T && cnt >= 0 && cnt < MX)
            srcs[(ci * T + dst) * MX + cnt] = src;
        return;
    }
    idx -= 2 * nedges;
    if (idx < T) {                             // flag via bsearch of sorted a2a
        int lo = 0, hi = a2len, pos = -1;
        while (lo < hi) {
            const int mid = (lo + hi) >> 1;
            const int v = a2a[mid];
            if (v == idx) { pos = mid; break; }
            if (v < idx) lo = mid + 1; else hi = mid;
        }
        flag[idx] = pos;
    }
}

// ---------------------------------------------------------------------------
// Kernel 1: QKV projection, 32-token tile, 192 threads/block.
// Thread = (token-half g, channel o in 0..95); owns output channels o and
// o+96 -> each LDS float4 read feeds 8 FMAs (was 4) — LDS-issue pressure
// halved, inner loop becomes VALU-bound.
// Outputs:
//  - sparse channels (c<40, model ch 32..71) channel-major:
//      XS[((c)*BS + b)*T + t]   -> coalesced staging for the attn kernel
//  - dense channels (c>=40, ch 72..95) compacted for a2a tokens:
//      Xg[(b*A2MAX + pos)*24 + (c-40)]
// ---------------------------------------------------------------------------
__global__ void qkv_kernel(const float* __restrict__ x, const float* __restrict__ WT,
                           const int* __restrict__ flag,
                           float* __restrict__ QS, float* __restrict__ KS,
                           float* __restrict__ VS,
                           float* __restrict__ Qg, float* __restrict__ Kg,
                           float* __restrict__ Vg) {
    const int tid  = threadIdx.x;              // 0..191
    const int base = blockIdx.x * QKV_TOK;     // grid = BT/32; all tokens same b
    __shared__ float xs[QKV_TOK * D];          // 12 KB
    float4* xs4 = (float4*)xs;
    const float4* xg = (const float4*)(x + base * D);
    #pragma unroll
    for (int i = 0; i < 4; ++i) xs4[tid + 192 * i] = xg[tid + 192 * i];
    __syncthreads();
    const int g = tid / 96;                    // token half 0/1
    const int o = tid - 96 * g;                // 0..95
    float acc0[16], acc1[16];
    const float bias0 = WT[96 * 192 + o];
    const float bias1 = WT[96 * 192 + o + 96];
    #pragma unroll
    for (int j = 0; j < 16; ++j) { acc0[j] = bias0; acc1[j] = bias1; }
    #pragma unroll 2
    for (int i4 = 0; i4 < 24; ++i4) {
        const float* wr = WT + 4 * i4 * 192;
        const float w00 = wr[o],       w01 = wr[192 + o],
                    w02 = wr[384 + o], w03 = wr[576 + o];
        const float w10 = wr[o + 96],       w11 = wr[192 + o + 96],
                    w12 = wr[384 + o + 96], w13 = wr[576 + o + 96];
        #pragma unroll
        for (int j = 0; j < 16; ++j) {
            const float4 xv = xs4[(g * 16 + j) * 24 + i4];
            acc0[j] += w00 * xv.x + w01 * xv.y + w02 * xv.z + w03 * xv.w;
            acc1[j] += w10 * xv.x + w11 * xv.y + w12 * xv.z + w13 * xv.w;
        }
    }
    const int b    = base >> 9;
    const int tloc = (base & (T - 1)) + g * 16;

#define STORE_CH(CH, ACC)                                                     \
    {                                                                         \
        const int part = (CH) >> 6, c = (CH) & 63;                            \
        if (c < 40) {                                                         \
            float* XS = (part == 0) ? QS : (part == 1 ? KS : VS);             \
            float4* dp = (float4*)(XS + ((size_t)c * BS + b) * T + tloc);     \
            dp[0] = make_float4(ACC[0],  ACC[1],  ACC[2],  ACC[3]);           \
            dp[1] = make_float4(ACC[4],  ACC[5],  ACC[6],  ACC[7]);           \
            dp[2] = make_float4(ACC[8],  ACC[9],  ACC[10], ACC[11]);          \
            dp[3] = make_float4(ACC[12], ACC[13], ACC[14], ACC[15]);          \
        } else {                                                              \
            float* gb = (part == 0) ? Qg : (part == 1 ? Kg : Vg);             \
            _Pragma("unroll")                                                 \
            for (int j = 0; j < 16; ++j) {                                    \
                const int ps = flag[tloc + j];                                \
                if (ps >= 0)                                                  \
                    gb[((size_t)b * A2MAX + ps) * 24 + (c - 40)] = ACC[j];    \
            }                                                                 \
        }                                                                     \
    }
    STORE_CH(o, acc0)
    STORE_CH(o + 96, acc1)
#undef STORE_CH
}

// ---------------------------------------------------------------------------
// Kernel 2: merged attention. grid (9, BS) x 512 threads.
//  blockIdx.x < 8 : sparse L1 attention for (ci = x>>2, h = x&3)  [as before]
//  blockIdx.x == 8: dense L1 attention over ALL a2len tokens (600 work items
//                   looped over 512 threads). Dense work is fully hidden
//                   under the concurrently-running sparse blocks.
// Shared memory is a union: sparse 20.5 KB, dense 41.6 KB.
// ---------------------------------------------------------------------------
__global__ __launch_bounds__(512)
void attn_kernel(const float* __restrict__ QS, const float* __restrict__ KS,
                 const float* __restrict__ VS, const int* __restrict__ srcs,
                 const float* __restrict__ Qg, const float* __restrict__ Kg,
                 const float* __restrict__ Vg, const int* __restrict__ a2a,
                 int a2len, int extra, float* __restrict__ B) {
    __shared__ float smem[A2MAX + 2 * A2MAX * 32];   // 41.6 KB (dense view)
    const int b   = blockIdx.y;
    const int tid = threadIdx.x;               // 0..511

    if (blockIdx.x < 8) {
        // ---------------- sparse path ----------------
        const int ci = blockIdx.x >> 2, h = blockIdx.x & 3;
        const int cb = 20 * ci + 5 * h;        // channel base within the 40
        float* ks = smem;                      // [5][T]
        float* vs = smem + 5 * T;
        const size_t rowbase = ((size_t)cb * BS + b) * T;
        #pragma unroll
        for (int i = tid; i < 5 * T; i += 512) {
            const int w = i >> 9, s = i & (T - 1);
            ks[i] = KS[rowbase + (size_t)w * BS * T + s];
            vs[i] = VS[rowbase + (size_t)w * BS * T + s];
        }
        __syncthreads();
        const float iscale = 0.4472135954999579f;  // 1/sqrt(5)
        const int t = tid;
        const float q0 = QS[rowbase + 0 * BS * T + t];
        const float q1 = QS[rowbase + 1 * BS * T + t];
        const float q2 = QS[rowbase + 2 * BS * T + t];
        const float q3 = QS[rowbase + 3 * BS * T + t];
        const float q4 = QS[rowbase + 4 * BS * T + t];
        const int4* sp4 = (const int4*)(srcs + (ci * T + t) * MX);
        float l = 0.f, o0 = 0.f, o1 = 0.f, o2 = 0.f, o3 = 0.f, o4 = 0.f;
        #pragma unroll 2
        for (int c4 = 0; c4 < MX / 4; ++c4) {
            const int4 s4 = sp4[c4];
            const int sv[4] = {s4.x, s4.y, s4.z, s4.w};
            #pragma unroll
            for (int m = 0; m < 4; ++m) {
                const int s = sv[m];
                if (s < 0) continue;           // empty slot (-1e12)
                const float sum = fabsf(q0 - ks[s]) + fabsf(q1 - ks[T + s]) +
                                  fabsf(q2 - ks[2 * T + s]) + fabsf(q3 - ks[3 * T + s]) +
                                  fabsf(q4 - ks[4 * T + s]);
                const float e = __expf(-sum * iscale);
                l  += e;
                o0 += e * vs[s];         o1 += e * vs[T + s];
                o2 += e * vs[2 * T + s]; o3 += e * vs[3 * T + s];
                o4 += e * vs[4 * T + s];
            }
        }
        const float inv = (l > 0.f) ? 1.f / l : 0.f;
        float* bp = B + ((size_t)b * T + t) * 96 + 32 + cb;
        bp[0] = o0 * inv; bp[1] = o1 * inv; bp[2] = o2 * inv;
        bp[3] = o3 * inv; bp[4] = o4 * inv;
        return;
    }

    // ---------------- dense path (blockIdx.x == 8) ----------------
    int*   rows = (int*)smem;                  // [A2MAX]
    float* ks   = smem + A2MAX;                // [A2MAX][32], 16B-aligned
    float* vs   = ks + A2MAX * 32;
    for (int i = tid; i < a2len; i += 512) rows[i] = a2a[i];
    const int nq = (a2len * 24) / 4;           // 900 float4s
    const float4* kg4 = (const float4*)(Kg + (size_t)b * A2MAX * 24);
    const float4* vg4 = (const float4*)(Vg + (size_t)b * A2MAX * 24);
    for (int idx = tid; idx < nq; idx += 512) {
        const int s = idx / 6, r = idx - 6 * s;
        const float4 kk = kg4[idx];
        const float4 vv = vg4[idx];
        const float kv[4]  = {kk.x, kk.y, kk.z, kk.w};
        const float vv4[4] = {vv.x, vv.y, vv.z, vv.w};
        #pragma unroll
        for (int m = 0; m < 4; ++m) {
            const int w = r * 4 + m, hh = w / 6, ww = w - 6 * hh;
            ks[s * 32 + hh * 8 + ww] = kv[m];
            vs[s * 32 + hh * 8 + ww] = vv4[m];
        }
    }
    __syncthreads();
    const float scale = 0.4082482904638631f;   // 1/sqrt(6)
    for (int item = tid; item < 4 * a2len; item += 512) {
        const int h = item & 3, d = item >> 2;
        const float* qp = Qg + ((size_t)b * A2MAX + d) * 24 + h * 6;
        const float q0 = qp[0], q1 = qp[1], q2 = qp[2],
                    q3 = qp[3], q4 = qp[4], q5 = qp[5];
        float l = 0.f, o0 = 0.f, o1 = 0.f, o2 = 0.f, o3 = 0.f, o4 = 0.f, o5 = 0.f;
        for (int s = 0; s < a2len; ++s) {
            const float4 k4 = *(const float4*)&ks[s * 32 + h * 8];
            const float2 k2 = *(const float2*)&ks[s * 32 + h * 8 + 4];
            const float sum = fabsf(q0 - k4.x) + fabsf(q1 - k4.y) + fabsf(q2 - k4.z) +
                              fabsf(q3 - k4.w) + fabsf(q4 - k2.x) + fabsf(q5 - k2.y);
            const float e = __expf(-sum * scale);
            const float4 v4 = *(const float4*)&vs[s * 32 + h * 8];
            const float2 v2 = *(const float2*)&vs[s * 32 + h * 8 + 4];
            l  += e;
            o0 += e * v4.x; o1 += e * v4.y; o2 += e * v4.z;
            o3 += e * v4.w; o4 += e * v2.x; o5 += e * v2.y;
        }
        if (extra) {                           // zero-pad key row
            const float sum = fabsf(q0) + fabsf(q1) + fabsf(q2) +
                              fabsf(q3) + fabsf(q4) + fabsf(q5);
            l += __expf(-sum * scale);
        }
        const float inv = 1.f / l;
        float* bp = B + ((size_t)b * T + rows[d]) * 96 + 72 + h * 6;
        bp[0] = o0 * inv; bp[1] = o1 * inv; bp[2] = o2 * inv;
        bp[3] = o3 * inv; bp[4] = o4 * inv; bp[5] = o5 * inv;
    }
}

// ---------------------------------------------------------------------------
// Kernel 3: yb = silu-gate(B); out = x + FWT^T @ yb + bias. 16-token tile.
// Thread = (4-token group g, output o in 0..47); owns outputs o and o+48 ->
// each LDS float4 read feeds 8 FMAs (was 4). Channels 0..31 of B are hard
// zeros -> loop covers 32..95 only. Dense channels (>=72) of non-a2a tokens
// were never written -> masked via flag.
// ---------------------------------------------------------------------------
__global__ void fuse_kernel(const float* __restrict__ x, const float* __restrict__ FWT,
                            const float* __restrict__ B, const int* __restrict__ flag,
                            float* __restrict__ out) {
    const int tid  = threadIdx.x;              // 0..191
    const int base = blockIdx.x * FUSE_TOK;    // grid = BT/16
    __shared__ float yb[FUSE_TOK * 64];        // 4 KB, channels 32..95
    float4* yb4 = (float4*)yb;
    for (int idx = tid; idx < FUSE_TOK * 64; idx += 192) {
        const int j = idx >> 6, k = idx & 63;
        float v = B[(base + j) * 96 + 32 + k];
        if (k >= 40 && flag[(base + j) & (T - 1)] < 0) v = 0.f;  // unwritten dense ch
        yb[idx] = v / (1.f + __expf(-1.702f * v));
    }
    __syncthreads();
    const int g = tid / 48;                    // 0..3: 4-token group
    const int o = tid - 48 * g;                // 0..47
    float acc0[4], acc1[4];
    const float bias0 = FWT[64 * 96 + o];
    const float bias1 = FWT[64 * 96 + o + 48];
    #pragma unroll
    for (int j = 0; j < 4; ++j) { acc0[j] = bias0; acc1[j] = bias1; }
    #pragma unroll 2
    for (int i4 = 0; i4 < 16; ++i4) {
        const float* fr = FWT + 4 * i4 * 96;
        const float w00 = fr[o],          w01 = fr[96 + o],
                    w02 = fr[192 + o],    w03 = fr[288 + o];
        const float w10 = fr[o + 48],     w11 = fr[96 + o + 48],
                    w12 = fr[192 + o + 48], w13 = fr[288 + o + 48];
        #pragma unroll
        for (int j = 0; j < 4; ++j) {
            const float4 yv = yb4[(4 * g + j) * 16 + i4];
            acc0[j] += w00 * yv.x + w01 * yv.y + w02 * yv.z + w03 * yv.w;
            acc1[j] += w10 * yv.x + w11 * yv.y + w12 * yv.z + w13 * yv.w;
        }
    }
    #pragma unroll
    for (int j = 0; j < 4; ++j) {
        const int token = base + 4 * g + j;
        out[token * D + o]      = x[token * D + o]      + acc0[j];
        out[token * D + o + 48] = x[token * D + o + 48] + acc1[j];
    }
}

// ---------------------------------------------------------------------------
extern "C" void kernel_launch(void* const* d_in, const int* in_sizes, int n_in,
                              void* d_out, int out_size, void* d_ws, size_t ws_size,
                              hipStream_t stream) {
    const float* x   = (const float*)d_in[0];
    const float* wqv = (const float*)d_in[1];
    const float* fw  = (const float*)d_in[2];
    const int*  coo0 = (const int*)d_in[3];
    const int*  coo1 = (const int*)d_in[4];
    const int*  a2a  = (const int*)d_in[5];
    int a2len        = in_sizes[5];            // 150
    if (a2len > A2MAX) a2len = A2MAX;          // LDS/scratch capacity guard
    const int nedges = in_sizes[3] / 3;        // 16384

    // Workspace: QS|KS|VS (40*BS*T each) | Bb (BT*96) | Qg|Kg|Vg | srcs | flag | WT | FWT
    float* QS  = (float*)d_ws;
    float* KS  = QS + (size_t)40 * BS * T;
    float* VS  = KS + (size_t)40 * BS * T;
    float* Bb  = VS + (size_t)40 * BS * T;
    float* Qg  = Bb + (size_t)BT * 96;
    float* Kg  = Qg + (size_t)BS * A2MAX * 24;
    float* Vg  = Kg + (size_t)BS * A2MAX * 24;
    int*  srcs = (int*)(Vg + (size_t)BS * A2MAX * 24);
    int*  flag = srcs + 2 * T * MX;
    float* WT  = (float*)(flag + T);
    float* FWT = WT + 97 * 192;

    // No memset: srcs slots are fully covered by the COO scatter (dst/cnt
    // enumerate every slot); flag is computed directly in prep via bsearch.
    const int prep_n = 97 * 192 + 65 * 96 + 2 * nedges + T;
    prep_kernel<<<(prep_n + 255) / 256, 256, 0, stream>>>(
        wqv, fw, coo0, coo1, a2a, nedges, a2len, WT, FWT, srcs, flag);
    qkv_kernel<<<BT / QKV_TOK, 192, 0, stream>>>(x, WT, flag, QS, KS, VS, Qg, Kg, Vg);
    const int padl  = (a2len + 15) / 16 * 16;
    const int extra = (padl > a2len) ? 1 : 0;
    attn_kernel<<<dim3(9, BS), 512, 0, stream>>>(
        QS, KS, VS, srcs, Qg, Kg, Vg, a2a, a2len, extra, Bb);
    fuse_kernel<<<BT / FUSE_TOK, 192, 0, stream>>>(x, FWT, Bb, flag, (float*)d_out);
}

// Round 3
// 131.092 us; speedup vs baseline: 1.0532x; 1.0532x over previous
//
#include <hip/hip_runtime.h>
#include <hip/hip_bf16.h>
#include <math.h>

#define BS    32
#define T     512
#define BT    (BS * T)     // 16384 tokens
#define D     96
#define H     4
#define MX    32           // DST_MXLEN
#define A2MAX 160          // padl for a2len=150

#define QKV_TOK  16        // tokens per qkv block
#define FUSE_TOK 16        // tokens per fuse block

// ---------------------------------------------------------------------------
// Kernel 0 (prep): weight transposes + COO scatter + a2a position flags.
// WT  [97][192]: WT[i*192 + p*64 + c] = wqv[(p*96+32+c)*97 + i]  (i=96 -> bias)
// FWT [65][96] : FWT[i*96 + o]        = fw[o*97 + 32 + i]        (i=64 -> bias)
// srcs[(ci*T+dst)*MX + cnt] = src.
//   No memset needed: the problem's COO covers EVERY (dst,cnt) slot exactly
//   once (dst=repeat(arange(T),MX), cnt=tile(arange(MX))).
// flag[t]: race-free binary search of sorted a2a (validated round 1).
// ---------------------------------------------------------------------------
__global__ void prep_kernel(const float* __restrict__ wqv, const float* __restrict__ fw,
                            const int* __restrict__ coo0, const int* __restrict__ coo1,
                            const int* __restrict__ a2a, int nedges, int a2len,
                            float* __restrict__ WT, float* __restrict__ FWT,
                            int* __restrict__ srcs, int* __restrict__ flag) {
    int idx = blockIdx.x * blockDim.x + threadIdx.x;
    if (idx < 97 * 192) {
        const int i = idx / 192, oc = idx - 192 * i;
        const int p = oc >> 6, c = oc & 63;
        WT[idx] = wqv[(p * 96 + 32 + c) * 97 + i];
        return;
    }
    idx -= 97 * 192;
    if (idx < 65 * 96) {
        const int i = idx / 96, o = idx - 96 * i;
        FWT[idx] = fw[o * 97 + 32 + i];
        return;
    }
    idx -= 65 * 96;
    if (idx < 2 * nedges) {
        const int ci = idx / nedges;
        const int e  = idx - ci * nedges;
        const int* row = (ci == 0 ? coo0 : coo1) + e * 3;
        const int dst = row[0], src = row[1], cnt = row[2];
        if (dst >= 0 && dst < T && cnt >= 0 && cnt < MX)
            srcs[(ci * T + dst) * MX + cnt] = src;
        return;
    }
    idx -= 2 * nedges;
    if (idx < T) {                             // flag via bsearch of sorted a2a
        int lo = 0, hi = a2len, pos = -1;
        while (lo < hi) {
            const int mid = (lo + hi) >> 1;
            const int v = a2a[mid];
            if (v == idx) { pos = mid; break; }
            if (v < idx) lo = mid + 1; else hi = mid;
        }
        flag[idx] = pos;
    }
}

// ---------------------------------------------------------------------------
// Kernel 1: QKV projection, 16-token register tile, 192 threads/block.
// (round-0 version, verbatim — proven fastest so far)
// Outputs:
//  - sparse channels (c<40, model ch 32..71) channel-major:
//      XS[((c)*BS + b)*T + t]   -> coalesced staging for attn kernel
//  - dense channels (c>=40, ch 72..95) compacted for a2a tokens:
//      Xg[(b*A2MAX + pos)*24 + (c-40)]
// ---------------------------------------------------------------------------
__global__ void qkv_kernel(const float* __restrict__ x, const float* __restrict__ WT,
                           const int* __restrict__ flag,
                           float* __restrict__ QS, float* __restrict__ KS,
                           float* __restrict__ VS,
                           float* __restrict__ Qg, float* __restrict__ Kg,
                           float* __restrict__ Vg) {
    const int tid  = threadIdx.x;              // 0..191
    const int base = blockIdx.x * QKV_TOK;     // grid = BT/16; all tokens same b
    __shared__ float xs[QKV_TOK * D];          // 6 KB
    float4* xs4 = (float4*)xs;
    const float4* xg = (const float4*)(x + base * D);
    xs4[tid]       = xg[tid];
    xs4[tid + 192] = xg[tid + 192];
    __syncthreads();
    float acc[QKV_TOK];
    const float bias = WT[96 * 192 + tid];
    #pragma unroll
    for (int j = 0; j < QKV_TOK; ++j) acc[j] = bias;
    #pragma unroll 3
    for (int i4 = 0; i4 < 24; ++i4) {
        const float w0 = WT[(4 * i4 + 0) * 192 + tid];
        const float w1 = WT[(4 * i4 + 1) * 192 + tid];
        const float w2 = WT[(4 * i4 + 2) * 192 + tid];
        const float w3 = WT[(4 * i4 + 3) * 192 + tid];
        #pragma unroll
        for (int j = 0; j < QKV_TOK; ++j) {
            const float4 xv = xs4[j * 24 + i4];
            acc[j] += w0 * xv.x + w1 * xv.y + w2 * xv.z + w3 * xv.w;
        }
    }
    const int part = tid >> 6, c = tid & 63;
    const int b    = base >> 9;
    const int tloc = base & (T - 1);
    if (c < 40) {                              // sparse channels, channel-major
        float* XS = (part == 0) ? QS : (part == 1 ? KS : VS);
        float4* dp = (float4*)(XS + ((size_t)c * BS + b) * T + tloc);
        #pragma unroll
        for (int m = 0; m < 4; ++m)
            dp[m] = make_float4(acc[4 * m], acc[4 * m + 1],
                                acc[4 * m + 2], acc[4 * m + 3]);
    } else {                                   // dense channels, compact a2a rows
        float* g = (part == 0) ? Qg : (part == 1 ? Kg : Vg);
        #pragma unroll
        for (int j = 0; j < QKV_TOK; ++j) {
            const int ps = flag[tloc + j];
            if (ps >= 0) g[((size_t)b * A2MAX + ps) * 24 + (c - 40)] = acc[j];
        }
    }
}

// ---------------------------------------------------------------------------
// Kernel 2: merged attention. grid (10, BS) x 512 threads.
//  blockIdx.x < 8 : sparse L1 attention for (ci = x>>2, h = x&3)
//                   (round-0 sparse kernel, verbatim)
//  blockIdx.x >= 8: dense L1 attention; ONE (d,h) item per thread
//                   (item = (x-8)*512 + tid, single key-loop pass, no
//                   straggler). Runs concurrently with the sparse blocks.
// Shared memory union: sparse 20 KB, dense 41 KB.
// ---------------------------------------------------------------------------
__global__ __launch_bounds__(512)
void attn_kernel(const float* __restrict__ QS, const float* __restrict__ KS,
                 const float* __restrict__ VS, const int* __restrict__ srcs,
                 const float* __restrict__ Qg, const float* __restrict__ Kg,
                 const float* __restrict__ Vg, const int* __restrict__ a2a,
                 int a2len, int extra, float* __restrict__ B) {
    __shared__ __align__(16) float smem[2 * A2MAX * 32];   // 41 KB (dense view)
    const int b   = blockIdx.y;
    const int tid = threadIdx.x;               // 0..511

    if (blockIdx.x < 8) {
        // ---------------- sparse path (round-0 verbatim) ----------------
        const int ci = blockIdx.x >> 2, h = blockIdx.x & 3;
        const int cb = 20 * ci + 5 * h;        // channel base within the 40
        float* ks = smem;                      // [5][T]
        float* vs = smem + 5 * T;
        const size_t rowbase = ((size_t)cb * BS + b) * T;
        #pragma unroll
        for (int i = tid; i < 5 * T; i += 512) {
            const int w = i >> 9, s = i & (T - 1);
            ks[i] = KS[rowbase + (size_t)w * BS * T + s];
            vs[i] = VS[rowbase + (size_t)w * BS * T + s];
        }
        __syncthreads();
        const float iscale = 0.4472135954999579f;  // 1/sqrt(5)
        const int t = tid;
        const float q0 = QS[rowbase + 0 * BS * T + t];
        const float q1 = QS[rowbase + 1 * BS * T + t];
        const float q2 = QS[rowbase + 2 * BS * T + t];
        const float q3 = QS[rowbase + 3 * BS * T + t];
        const float q4 = QS[rowbase + 4 * BS * T + t];
        const int4* sp4 = (const int4*)(srcs + (ci * T + t) * MX);
        float l = 0.f, o0 = 0.f, o1 = 0.f, o2 = 0.f, o3 = 0.f, o4 = 0.f;
        #pragma unroll 2
        for (int c4 = 0; c4 < MX / 4; ++c4) {
            const int4 s4 = sp4[c4];
            const int sv[4] = {s4.x, s4.y, s4.z, s4.w};
            #pragma unroll
            for (int m = 0; m < 4; ++m) {
                const int s = sv[m];
                if (s < 0) continue;           // empty slot (-1e12)
                const float sum = fabsf(q0 - ks[s]) + fabsf(q1 - ks[T + s]) +
                                  fabsf(q2 - ks[2 * T + s]) + fabsf(q3 - ks[3 * T + s]) +
                                  fabsf(q4 - ks[4 * T + s]);
                const float e = __expf(-sum * iscale);
                l  += e;
                o0 += e * vs[s];         o1 += e * vs[T + s];
                o2 += e * vs[2 * T + s]; o3 += e * vs[3 * T + s];
                o4 += e * vs[4 * T + s];
            }
        }
        const float inv = (l > 0.f) ? 1.f / l : 0.f;
        float* bp = B + ((size_t)b * T + t) * 96 + 32 + cb;
        bp[0] = o0 * inv; bp[1] = o1 * inv; bp[2] = o2 * inv;
        bp[3] = o3 * inv; bp[4] = o4 * inv;
        return;
    }

    // ---------------- dense path (blockIdx.x == 8, 9) ----------------
    float* ks = smem;                          // [A2MAX][32]
    float* vs = smem + A2MAX * 32;
    const int nq = (a2len * 24) / 4;           // 900 float4s
    const float4* kg4 = (const float4*)(Kg + (size_t)b * A2MAX * 24);
    const float4* vg4 = (const float4*)(Vg + (size_t)b * A2MAX * 24);
    for (int idx = tid; idx < nq; idx += 512) {
        const int s = idx / 6, r = idx - 6 * s;
        const float4 kk = kg4[idx];
        const float4 vv = vg4[idx];
        const float kv[4]  = {kk.x, kk.y, kk.z, kk.w};
        const float vv4[4] = {vv.x, vv.y, vv.z, vv.w};
        #pragma unroll
        for (int m = 0; m < 4; ++m) {
            const int w = r * 4 + m, hh = w / 6, ww = w - 6 * hh;
            ks[s * 32 + hh * 8 + ww] = kv[m];
            vs[s * 32 + hh * 8 + ww] = vv4[m];
        }
    }
    __syncthreads();
    const int item = (blockIdx.x - 8) * 512 + tid;
    if (item >= 4 * a2len) return;
    const int h = item & 3, d = item >> 2;
    const float scale = 0.4082482904638631f;   // 1/sqrt(6)
    const float* qp = Qg + ((size_t)b * A2MAX + d) * 24 + h * 6;
    const float q0 = qp[0], q1 = qp[1], q2 = qp[2],
                q3 = qp[3], q4 = qp[4], q5 = qp[5];
    float l = 0.f, o0 = 0.f, o1 = 0.f, o2 = 0.f, o3 = 0.f, o4 = 0.f, o5 = 0.f;
    for (int s = 0; s < a2len; ++s) {
        const float4 k4 = *(const float4*)&ks[s * 32 + h * 8];
        const float2 k2 = *(const float2*)&ks[s * 32 + h * 8 + 4];
        const float sum = fabsf(q0 - k4.x) + fabsf(q1 - k4.y) + fabsf(q2 - k4.z) +
                          fabsf(q3 - k4.w) + fabsf(q4 - k2.x) + fabsf(q5 - k2.y);
        const float e = __expf(-sum * scale);
        const float4 v4 = *(const float4*)&vs[s * 32 + h * 8];
        const float2 v2 = *(const float2*)&vs[s * 32 + h * 8 + 4];
        l  += e;
        o0 += e * v4.x; o1 += e * v4.y; o2 += e * v4.z;
        o3 += e * v4.w; o4 += e * v2.x; o5 += e * v2.y;
    }
    if (extra) {                               // zero-pad key row
        const float sum = fabsf(q0) + fabsf(q1) + fabsf(q2) +
                          fabsf(q3) + fabsf(q4) + fabsf(q5);
        l += __expf(-sum * scale);
    }
    const float inv = 1.f / l;
    float* bp = B + ((size_t)b * T + a2a[d]) * 96 + 72 + h * 6;
    bp[0] = o0 * inv; bp[1] = o1 * inv; bp[2] = o2 * inv;
    bp[3] = o3 * inv; bp[4] = o4 * inv; bp[5] = o5 * inv;
}

// ---------------------------------------------------------------------------
// Kernel 3: yb = silu-gate(B); out = x + FWT^T @ yb + bias. 16-token tile.
// (round-0 version, verbatim)
// ---------------------------------------------------------------------------
__global__ void fuse_kernel(const float* __restrict__ x, const float* __restrict__ FWT,
                            const float* __restrict__ B, const int* __restrict__ flag,
                            float* __restrict__ out) {
    const int tid  = threadIdx.x;              // 0..191
    const int half = tid / 96;                 // token-lane 0/1
    const int o    = tid - 96 * half;
    const int base = blockIdx.x * FUSE_TOK;    // grid = BT/16
    __shared__ float yb[FUSE_TOK * 64];        // 4 KB, channels 32..95
    float4* yb4 = (float4*)yb;
    for (int idx = tid; idx < FUSE_TOK * 64; idx += 192) {
        const int j = idx >> 6, k = idx & 63;
        float v = B[(base + j) * 96 + 32 + k];
        if (k >= 40 && flag[(base + j) & (T - 1)] < 0) v = 0.f;  // unwritten dense ch
        yb[idx] = v / (1.f + __expf(-1.702f * v));
    }
    __syncthreads();
    float acc[FUSE_TOK / 2];
    const float bias = FWT[64 * 96 + o];
    #pragma unroll
    for (int j = 0; j < FUSE_TOK / 2; ++j) acc[j] = bias;
    #pragma unroll 2
    for (int i4 = 0; i4 < 16; ++i4) {
        const float w0 = FWT[(4 * i4 + 0) * 96 + o];
        const float w1 = FWT[(4 * i4 + 1) * 96 + o];
        const float w2 = FWT[(4 * i4 + 2) * 96 + o];
        const float w3 = FWT[(4 * i4 + 3) * 96 + o];
        #pragma unroll
        for (int j = 0; j < FUSE_TOK / 2; ++j) {
            const float4 yv = yb4[(2 * j + half) * 16 + i4];
            acc[j] += w0 * yv.x + w1 * yv.y + w2 * yv.z + w3 * yv.w;
        }
    }
    #pragma unroll
    for (int j = 0; j < FUSE_TOK / 2; ++j) {
        const int token = base + 2 * j + half;
        out[token * D + o] = x[token * D + o] + acc[j];
    }
}

// ---------------------------------------------------------------------------
extern "C" void kernel_launch(void* const* d_in, const int* in_sizes, int n_in,
                              void* d_out, int out_size, void* d_ws, size_t ws_size,
                              hipStream_t stream) {
    const float* x   = (const float*)d_in[0];
    const float* wqv = (const float*)d_in[1];
    const float* fw  = (const float*)d_in[2];
    const int*  coo0 = (const int*)d_in[3];
    const int*  coo1 = (const int*)d_in[4];
    const int*  a2a  = (const int*)d_in[5];
    int a2len        = in_sizes[5];            // 150
    if (a2len > A2MAX) a2len = A2MAX;          // LDS/scratch capacity guard
    const int nedges = in_sizes[3] / 3;        // 16384

    // Workspace: QS|KS|VS (40*BS*T each) | Bb (BT*96) | Qg|Kg|Vg | srcs | flag | WT | FWT
    float* QS  = (float*)d_ws;
    float* KS  = QS + (size_t)40 * BS * T;
    float* VS  = KS + (size_t)40 * BS * T;
    float* Bb  = VS + (size_t)40 * BS * T;
    float* Qg  = Bb + (size_t)BT * 96;
    float* Kg  = Qg + (size_t)BS * A2MAX * 24;
    float* Vg  = Kg + (size_t)BS * A2MAX * 24;
    int*  srcs = (int*)(Vg + (size_t)BS * A2MAX * 24);
    int*  flag = srcs + 2 * T * MX;
    float* WT  = (float*)(flag + T);
    float* FWT = WT + 97 * 192;

    // No memset: srcs fully covered by the COO scatter; flag computed in prep.
    const int prep_n = 97 * 192 + 65 * 96 + 2 * nedges + T;
    prep_kernel<<<(prep_n + 255) / 256, 256, 0, stream>>>(
        wqv, fw, coo0, coo1, a2a, nedges, a2len, WT, FWT, srcs, flag);
    qkv_kernel<<<BT / QKV_TOK, 192, 0, stream>>>(x, WT, flag, QS, KS, VS, Qg, Kg, Vg);
    const int padl  = (a2len + 15) / 16 * 16;
    const int extra = (padl > a2len) ? 1 : 0;
    const int ndense = (4 * a2len + 511) / 512;          // 2 for a2len=150
    attn_kernel<<<dim3(8 + ndense, BS), 512, 0, stream>>>(
        QS, KS, VS, srcs, Qg, Kg, Vg, a2a, a2len, extra, Bb);
    fuse_kernel<<<BT / FUSE_TOK, 192, 0, stream>>>(x, FWT, Bb, flag, (float*)d_out);
}